// Round 23
// baseline (516.313 us; speedup 1.0000x reference)
//
#include <hip/hip_runtime.h>
#include <stdint.h>

#define N_HEADS   32
#define N_KV      8
#define HEAD_DIM  128
#define HIDDEN_DIM 4096
#define BSZ       2
#define SEQ       2048
#define TOT_HEADS 48
#define QKV_DIM   6144   // TOT_HEADS * HEAD_DIM
#define ROWS      4096   // BSZ * SEQ
#define ROPE_HEADS 40    // Q + K heads (V not rope'd)

typedef __attribute__((ext_vector_type(4)))  float f32x4;
typedef __attribute__((ext_vector_type(16))) float f32x16;
typedef __attribute__((ext_vector_type(8)))  short bf16x8;
typedef unsigned short u16;
typedef unsigned int   u32;

#define AS1 __attribute__((address_space(1)))
#define AS3 __attribute__((address_space(3)))

static __device__ __forceinline__ float bf16f(u16 u) { return __uint_as_float(((u32)u) << 16); }
static __device__ __forceinline__ u16 f2bf(float f) {
  u32 x = __float_as_uint(f);
  x += 0x7fffu + ((x >> 16) & 1u);   // round-to-nearest-even
  return (u16)(x >> 16);
}
static __device__ __forceinline__ u32 cvt_pk_bf16(float lo, float hi) {
  u32 r;
  asm("v_cvt_pk_bf16_f32 %0, %1, %2" : "=v"(r) : "v"(lo), "v"(hi));
  return r;
}
static __device__ __forceinline__ bf16x8 mk8(u32 a, u32 b, u32 c, u32 d) {
  union { u32 u[4]; bf16x8 v; } x;
  x.u[0] = a; x.u[1] = b; x.u[2] = c; x.u[3] = d;
  return x.v;
}
// VALU cross-half swap: a' = {a.lo, b.lo}, b' = {a.hi, b.hi}  (T12).
static __device__ __forceinline__ void pl32swap(u32& a, u32& b) {
  asm("v_permlane32_swap_b32 %0, %1" : "+v"(a), "+v"(b));
}
// Cross-half reduce helpers: xb produced by an OPAQUE v_mov so the register
// coalescer cannot alias it with xa (R17 bug: coalesced copy -> swap v,v).
static __device__ __forceinline__ float crosshalf_max(float v) {
  u32 xa = __float_as_uint(v), xb;
  asm("v_mov_b32 %0, %1" : "=v"(xb) : "v"(xa));
  pl32swap(xa, xb);
  return fmaxf(__uint_as_float(xa), __uint_as_float(xb));
}
static __device__ __forceinline__ float crosshalf_sum(float v) {
  u32 xa = __float_as_uint(v), xb;
  asm("v_mov_b32 %0, %1" : "=v"(xb) : "v"(xa));
  pl32swap(xa, xb);
  return __uint_as_float(xa) + __uint_as_float(xb);
}

#define SBAR()  do { __builtin_amdgcn_sched_barrier(0); __builtin_amdgcn_s_barrier(); \
                     __builtin_amdgcn_sched_barrier(0); } while (0)
#define LGKM0() do { asm volatile("s_waitcnt lgkmcnt(0)" ::: "memory"); \
                     __builtin_amdgcn_sched_barrier(0); } while (0)

// ---------------- fused cast f32 -> bf16 for all three inputs ----------------
__global__ void cast3_k(const float4* __restrict__ a, const float4* __restrict__ b,
                        const float4* __restrict__ c,
                        ushort4* __restrict__ oa, ushort4* __restrict__ ob,
                        ushort4* __restrict__ oc, int na, int nb, int nc) {
  int i = blockIdx.x * blockDim.x + threadIdx.x;
  const int stride = gridDim.x * blockDim.x;
  const int tot = na + nb + nc;
  for (; i < tot; i += stride) {
    const float4* s; ushort4* d; int j = i;
    if (j < na)           { s = a; d = oa; }
    else if (j < na + nb) { s = b; d = ob; j -= na; }
    else                  { s = c; d = oc; j -= na + nb; }
    const float4 v = s[j];
    ushort4 o;
    o.x = f2bf(v.x); o.y = f2bf(v.y); o.z = f2bf(v.z); o.w = f2bf(v.w);
    d[j] = o;
  }
}

// ---------------- RoPE cos/sin tables (S x 64, half-dim) ----------------
__global__ void rope_tables_k(float* __restrict__ ctab, float* __restrict__ stab) {
  int t = blockIdx.x * blockDim.x + threadIdx.x;
  if (t >= SEQ * 64) return;
  int s = t >> 6, i = t & 63;
  float inv = powf(10000.0f, -(float)i / 64.0f);
  float ang = (float)s * inv;
  float sv, cv;
  sincosf(ang, &sv, &cv);
  ctab[t] = cv; stab[t] = sv;
}

// ---------------- 128x128 bf16 GEMM (m97 structure, measured 954 TF) ----------------
// ldc = C row stride (allows writing a column slab of a wider matrix).
template<int F32OUT>
__global__ __launch_bounds__(256, 2)
void gemm_bt_k(const u16* __restrict__ A, const u16* __restrict__ Bw,
               void* __restrict__ C, int M, int N, int K, int ldc)
{
  __shared__ uint4 smA[1024];
  __shared__ uint4 smB[1024];
  const int tid = threadIdx.x;
  const int nbx = N >> 7;
  const int bm = (blockIdx.x / nbx) << 7;
  const int bn = (blockIdx.x % nbx) << 7;
  const int lane = tid & 63;
  const int wave = tid >> 6;
  const int wm = (wave >> 1) << 6;
  const int wn = (wave & 1) << 6;
  const int fr = lane & 15;   // fragment row/col within 16
  const int fq = lane >> 4;   // 0..3

  f32x4 acc[4][4];
#pragma unroll
  for (int i = 0; i < 4; ++i)
#pragma unroll
    for (int j = 0; j < 4; ++j)
      acc[i][j] = {0.f, 0.f, 0.f, 0.f};

  const int gl_r = lane >> 3;                  // row-within-8 for this lane
  const int gl_c = (lane & 7) ^ gl_r;          // pre-swizzled global chunk

  for (int k0 = 0; k0 < K; k0 += 64) {
#pragma unroll
    for (int i = 0; i < 4; ++i) {
      const int rbase = (wave << 5) + (i << 3);      // wave-uniform row base
      const int row = rbase + gl_r;
      const u16* gA = A  + (size_t)(bm + row) * K + k0 + (gl_c << 3);
      const u16* gB = Bw + (size_t)(bn + row) * K + k0 + (gl_c << 3);
      __builtin_amdgcn_global_load_lds((const AS1 u32*)gA, (AS3 u32*)&smA[rbase << 3], 16, 0, 0);
      __builtin_amdgcn_global_load_lds((const AS1 u32*)gB, (AS3 u32*)&smB[rbase << 3], 16, 0, 0);
    }
    __syncthreads();
#pragma unroll
    for (int kk = 0; kk < 2; ++kk) {
      bf16x8 af[4], bfr[4];
      const int cc = (kk << 2) + fq;
#pragma unroll
      for (int m = 0; m < 4; ++m) {
        const int row = wm + (m << 4) + fr;
        af[m] = *reinterpret_cast<const bf16x8*>(&smA[(row << 3) + (cc ^ (row & 7))]);
      }
#pragma unroll
      for (int n = 0; n < 4; ++n) {
        const int row = wn + (n << 4) + fr;
        bfr[n] = *reinterpret_cast<const bf16x8*>(&smB[(row << 3) + (cc ^ (row & 7))]);
      }
#pragma unroll
      for (int m = 0; m < 4; ++m)
#pragma unroll
        for (int n = 0; n < 4; ++n)
          acc[m][n] = __builtin_amdgcn_mfma_f32_16x16x32_bf16(af[m], bfr[n], acc[m][n], 0, 0, 0);
    }
    __syncthreads();
  }

  // epilogue: D[row][col], row = fq*4+i (+m*16), col = fr (+n*16)
  const int col0 = bn + wn + fr;
#pragma unroll
  for (int m = 0; m < 4; ++m) {
#pragma unroll
    for (int i = 0; i < 4; ++i) {
      const int row = bm + wm + (m << 4) + (fq << 2) + i;
      if (F32OUT) {
        float* rp = reinterpret_cast<float*>(C) + (size_t)row * ldc + col0;
#pragma unroll
        for (int n = 0; n < 4; ++n) rp[n << 4] = acc[m][n][i];
      } else {
        u16* rp = reinterpret_cast<u16*>(C) + (size_t)row * ldc + col0;
#pragma unroll
        for (int n = 0; n < 4; ++n) rp[n << 4] = f2bf(acc[m][n][i]);
      }
    }
  }
}

// ---------------- 256x256 bf16 GEMM, R23 2-PHASE merge of the m201 schedule ----------------
// Stage slots IDENTICAL to the validated 4-phase pipeline: SA(t+1,h1)@PhA(t);
// SB(t+2,h0)+SB(t+2,h1)+SA(t+2,h0)@PhB(t). PhA: 16 ds_reads (A-lo + B all) ->
// 32 MFMA (mlo x n). PhB: 8 ds_reads (A-hi) -> 32 MFMA (mhi x n). Barriers per
// K-tile: 8 -> 4. Gates (in-order retirement ledger, steady outstanding <= 8):
// vmcnt(8) at END of EACH phase -- PhA gate retires SA(t,h1) before PhB reads;
// PhB gate retires PhB(t-1)'s 6 loads before PhA(t+1) reads. Tail: vmcnt(0) at
// PhB(NT-2); none at NT-1. Prologue unchanged (14 loads, vmcnt(6)).
// WAR identical to validated layout (each overwrite >= 1 barrier after last read).
template<int F32OUT>
__global__ __launch_bounds__(512, 2)
void gemm256_k(const u16* __restrict__ A, const u16* __restrict__ Bw,
               void* __restrict__ C, int M, int N, int K, int ldc)
{
  extern __shared__ uint4 lds[];
  uint4* LA = lds;          // [2 buf][256 rows][8 chunks] = 4096 uint4 = 64 KB
  uint4* LB = lds + 4096;   // same
  const int NT = K >> 6;
  const int tid  = threadIdx.x;
  const int lane = tid & 63;
  const int wave = tid >> 6;
  const int nbx = N >> 8;
  const int cpx = gridDim.x >> 3;
  const int wg  = (blockIdx.x & 7) * cpx + (blockIdx.x >> 3);   // XCD swizzle (nwg%8==0)
  const int bm = (wg / nbx) << 8;
  const int bn = (wg % nbx) << 8;

  const int wm = (wave >> 2) << 7;   // 0 / 128
  const int wn = (wave & 3) << 6;    // 0,64,128,192
  const int fr = lane & 15;
  const int fq = lane >> 4;
  const int s7 = fr & 7;

  const int rA  = (wave << 3) + (lane >> 3);
  const int c8e = (((lane & 7) ^ (lane >> 3)) << 3);   // element offset

  auto SA = [&](int t, int h, int buf) {
    uint4* d = LA + (buf << 11) + (h << 10) + (wave << 6);
    const u16* s = A + (size_t)(bm + (h << 7) + rA) * K + (t << 6) + c8e;
    __builtin_amdgcn_global_load_lds((const AS1 u32*)s, (AS3 u32*)d, 16, 0, 0);
    __builtin_amdgcn_global_load_lds((const AS1 u32*)(s + (size_t)64 * K), (AS3 u32*)(d + 512), 16, 0, 0);
  };
  auto SB = [&](int t, int h, int buf) {
    uint4* d = LB + (buf << 11) + (h << 10) + (wave << 6);
    const u16* s = Bw + (size_t)(bn + (h << 7) + rA) * K + (t << 6) + c8e;
    __builtin_amdgcn_global_load_lds((const AS1 u32*)s, (AS3 u32*)d, 16, 0, 0);
    __builtin_amdgcn_global_load_lds((const AS1 u32*)(s + (size_t)64 * K), (AS3 u32*)(d + 512), 16, 0, 0);
  };

  f32x4 acc[8][4];
#pragma unroll
  for (int m = 0; m < 8; ++m)
#pragma unroll
    for (int n = 0; n < 4; ++n)
      acc[m][n] = {0.f, 0.f, 0.f, 0.f};

  // prologue: tile0 all 4 halves, tile1 B-h0,B-h1,A-h0 (A-h1(1) staged at PhA(0))
  SB(0, 0, 0); SB(0, 1, 0); SA(0, 0, 0); SA(0, 1, 0);
  SB(1, 0, 1); SB(1, 1, 1); SA(1, 0, 1);
  asm volatile("s_waitcnt vmcnt(6)" ::: "memory");
  SBAR();

  bf16x8 Af[4][2], Bf[4][2];

#pragma unroll 1
  for (int t = 0; t < NT; ++t) {
    const int buf  = t & 1;
    const int base = buf << 11;
    const int abase = base + ((wm + fr) << 3);
    const int bbase = base + ((wn + fr) << 3);

    // ---- PhA: read A-lo (8) + B all n (8); stage A-h1(t+1); MFMA mlo x n ----
#pragma unroll
    for (int m = 0; m < 4; ++m)
#pragma unroll
      for (int kk = 0; kk < 2; ++kk)
        Af[m][kk] = *reinterpret_cast<const bf16x8*>(&LA[abase + m * 128 + (((kk << 2) + fq) ^ s7)]);
#pragma unroll
    for (int n = 0; n < 4; ++n)
#pragma unroll
      for (int kk = 0; kk < 2; ++kk)
        Bf[n][kk] = *reinterpret_cast<const bf16x8*>(&LB[bbase + n * 128 + (((kk << 2) + fq) ^ s7)]);
    if (t + 1 < NT) SA(t + 1, 1, buf ^ 1);
    SBAR();
    LGKM0();
    __builtin_amdgcn_s_setprio(1);
#pragma unroll
    for (int m = 0; m < 4; ++m)
#pragma unroll
      for (int n = 0; n < 4; ++n)
#pragma unroll
        for (int kk = 0; kk < 2; ++kk)
          acc[m][n] = __builtin_amdgcn_mfma_f32_16x16x32_bf16(Af[m][kk], Bf[n][kk], acc[m][n], 0, 0, 0);
    __builtin_amdgcn_s_setprio(0);
    asm volatile("s_waitcnt vmcnt(8)" ::: "memory");   // retire SA(t,h1) for PhB
    SBAR();

    // ---- PhB: read A-hi (8); stage B-h0/h1(t+2)+A-h0(t+2); MFMA mhi x n; GATE ----
#pragma unroll
    for (int m = 0; m < 4; ++m)
#pragma unroll
      for (int kk = 0; kk < 2; ++kk)
        Af[m][kk] = *reinterpret_cast<const bf16x8*>(&LA[abase + 512 + m * 128 + (((kk << 2) + fq) ^ s7)]);
    if (t + 2 < NT) { SB(t + 2, 0, buf); SB(t + 2, 1, buf); SA(t + 2, 0, buf); }
    SBAR();
    LGKM0();
    __builtin_amdgcn_s_setprio(1);
#pragma unroll
    for (int m = 0; m < 4; ++m)
#pragma unroll
      for (int n = 0; n < 4; ++n)
#pragma unroll
        for (int kk = 0; kk < 2; ++kk)
          acc[4 + m][n] = __builtin_amdgcn_mfma_f32_16x16x32_bf16(Af[m][kk], Bf[n][kk], acc[4 + m][n], 0, 0, 0);
    __builtin_amdgcn_s_setprio(0);
    if (t < NT - 2)       { asm volatile("s_waitcnt vmcnt(8)" ::: "memory"); }
    else if (t == NT - 2) { asm volatile("s_waitcnt vmcnt(0)" ::: "memory"); }
    SBAR();
  }

  // epilogue: D row = bm+wm+m*16+fq*4+i, col = bn+wn+n*16+fr
  const int col0 = bn + wn + fr;
#pragma unroll
  for (int m = 0; m < 8; ++m) {
#pragma unroll
    for (int i = 0; i < 4; ++i) {
      const int row = bm + wm + (m << 4) + (fq << 2) + i;
      if (F32OUT) {
        float* rp = reinterpret_cast<float*>(C) + (size_t)row * ldc + col0;
#pragma unroll
        for (int n = 0; n < 4; ++n) rp[n << 4] = acc[m][n][i];
      } else {
        u16* rp = reinterpret_cast<u16*>(C) + (size_t)row * ldc + col0;
#pragma unroll
        for (int n = 0; n < 4; ++n) rp[n << 4] = f2bf(acc[m][n][i]);
      }
    }
  }
}

// ---------------- RoPE + scatter Q,K heads -> Q(B,H,S,D) K(B,KV,S,D) ----------------
// Q heads pre-scaled by 1/sqrt(128)*log2(e): scores leave QK^T in log2 domain.
__global__ void rope_scatter_k(const u16* __restrict__ QKV,
                               const float* __restrict__ ctab, const float* __restrict__ stab,
                               u16* __restrict__ Qo, u16* __restrict__ Ko)
{
  const int t = blockIdx.x * blockDim.x + threadIdx.x;  // ROWS*40*64 threads
  const int d = t & 63;
  const int hh = (t >> 6) % ROPE_HEADS;
  const int row = t / (64 * ROPE_HEADS);
  const int b = row >> 11, sq = row & (SEQ - 1);
  const u16* src = QKV + (size_t)row * QKV_DIM + hh * HEAD_DIM;
  const float x1 = bf16f(src[d]);
  const float x2 = bf16f(src[d + 64]);
  const float c = ctab[(sq << 6) + d], sn = stab[(sq << 6) + d];
  float y1 = x1 * c - x2 * sn;
  float y2 = x2 * c + x1 * sn;
  u16* dst;
  if (hh < N_HEADS) {
    const float SC2 = 0.1275170747f;   // (1/sqrt(128)) * log2(e)
    y1 *= SC2; y2 *= SC2;
    dst = Qo + ((size_t)(b * N_HEADS + hh) * SEQ + sq) * HEAD_DIM;
  } else {
    dst = Ko + ((size_t)(b * N_KV + (hh - N_HEADS)) * SEQ + sq) * HEAD_DIM;
  }
  dst[d] = f2bf(y1);
  dst[d + 64] = f2bf(y2);
}

// ---------------- V transpose: QKV cols [5120,6144) -> Vt[b][kv][d][s] ----------------
__global__ __launch_bounds__(256)
void vtrans_k(const u16* __restrict__ QKV, u16* __restrict__ Vt)
{
  __shared__ u16 tile[64][72];
  const int idx = blockIdx.x;           // dt(1) | st(5) | kv(3) | b(1)
  const int dt = idx & 1;
  const int st = (idx >> 1) & 31;
  const int kv = (idx >> 6) & 7;
  const int b  = idx >> 9;
  const int tid = threadIdx.x;
  const int s0 = st << 6, d0 = dt << 6;
  const int rl = tid >> 3, cc8 = (tid & 7) << 3;
#pragma unroll
  for (int p = 0; p < 2; ++p) {
    const int sl = rl + (p << 5);
    const u16* src = QKV + (size_t)(b * SEQ + s0 + sl) * QKV_DIM
                   + (N_HEADS + N_KV + kv) * HEAD_DIM + d0 + cc8;
    *reinterpret_cast<uint4*>(&tile[sl][cc8]) = *reinterpret_cast<const uint4*>(src);
  }
  __syncthreads();
#pragma unroll
  for (int p = 0; p < 2; ++p) {
    const int dl = rl + (p << 5);
    u16 tmp[8];
#pragma unroll
    for (int k2 = 0; k2 < 8; ++k2) tmp[k2] = tile[cc8 + k2][dl];
    u16* dst = Vt + ((size_t)(b * N_KV + kv) * HEAD_DIM + d0 + dl) * SEQ + s0 + cc8;
    *reinterpret_cast<uint4*>(dst) = *reinterpret_cast<const uint4*>(tmp);
  }
}

// ---------------- MFMA flash attention (causal GQA, KVBLK=64) ----------------
// R22 version (best measured): KVBLK=64, launch_bounds(512,2), V rows 8 chunks
// with rotation swizzle slot=(c+d)&7 (inverse on stage), permlane pack/reduce.
__global__ __launch_bounds__(512, 2)
void attn_mfma_k(const u16* __restrict__ Q, const u16* __restrict__ K,
                 const u16* __restrict__ Vt, u16* __restrict__ Out)
{
  __shared__ uint4 Ksm[2][1024];
  __shared__ uint4 Vsm[2][1024];
  const int tid  = threadIdx.x;
  const int lane = tid & 63;
  const int w    = tid >> 6;
  const int idx  = blockIdx.x;                    // qrev(5) | b(1) | kvh(3)
  const int kvh  = idx & 7;                       // XCD-pinned KV
  const int b    = (idx >> 3) & 1;
  const int qi   = 31 - (idx >> 4);               // heaviest q-tiles first
  const int q0   = qi << 6;                       // 64-row q-tile base
  const int head = w & 3;
  const int qsub = w >> 2;
  const int h    = (kvh << 2) + head;

  const int ql = lane & 31;
  const int hh = lane >> 5;

  const u16* Qh = Q  + (size_t)(b * N_HEADS + h) * SEQ * HEAD_DIM;
  const u16* Kb = K  + (size_t)(b * N_KV + kvh) * SEQ * HEAD_DIM;
  const u16* Vb = Vt + (size_t)(b * N_KV + kvh) * HEAD_DIM * SEQ;

  int koff[8];
#pragma unroll
  for (int f = 0; f < 8; ++f) koff[f] = (ql << 4) + (((f << 1) + hh) ^ (ql & 15));
  // V read offsets: row d = dblk*32+ql (8 chunks/row), slot = (2j+hh+d)&7 = (2j+hh+ql)&7
  int voff[4][4];
#pragma unroll
  for (int dblk = 0; dblk < 4; ++dblk)
#pragma unroll
    for (int j = 0; j < 4; ++j)
      voff[dblk][j] = ((((dblk << 5) + ql) << 3)) + (((j << 1) + hh + ql) & 7);

  auto stage = [&](int buf, int ks) {
#pragma unroll
    for (int p = 0; p < 2; ++p) {           // K: 64 rows x 16 chunks = 1024
      const int base = (p << 9) + (w << 6);
      const int sl2 = base + lane;
      const int row = sl2 >> 4, cs = sl2 & 15;
      const int g = cs ^ (row & 15);
      const u16* src = Kb + (size_t)(ks + row) * HEAD_DIM + (g << 3);
      __builtin_amdgcn_global_load_lds((const AS1 u32*)src, (AS3 u32*)&Ksm[buf][base], 16, 0, 0);
    }
#pragma unroll
    for (int p = 0; p < 2; ++p) {           // V: 128 rows x 8 chunks = 1024
      const int base = (p << 9) + (w << 6);
      const int sl2 = base + lane;
      const int d = sl2 >> 3, cs = sl2 & 7;
      const int g = (cs - d) & 7;           // inverse of read rotation
      const u16* src = Vb + (size_t)d * SEQ + ks + (g << 3);
      __builtin_amdgcn_global_load_lds((const AS1 u32*)src, (AS3 u32*)&Vsm[buf][base], 16, 0, 0);
    }
  };

  bf16x8 qf[8];
#pragma unroll
  for (int f = 0; f < 8; ++f)
    qf[f] = *reinterpret_cast<const bf16x8*>(Qh + (size_t)(q0 + (qsub << 5) + ql) * HEAD_DIM
                                             + 16 * f + 8 * hh);

  f32x16 o[4];
#pragma unroll
  for (int dblk = 0; dblk < 4; ++dblk)
#pragma unroll
    for (int r = 0; r < 16; ++r) o[dblk][r] = 0.f;
  float m2 = -1e30f, lsum = 0.f;

  stage(0, 0);

#pragma unroll 1
  for (int sb = 0; sb <= qi; ++sb) {
    const int cur = sb & 1;
    __syncthreads();          // drains stage(sb) (vmcnt 0); prev compute done
    if (sb < qi) stage(cur ^ 1, (sb + 1) << 6);   // prefetch under compute

    f32x16 T0, T1;
#pragma unroll
    for (int r = 0; r < 16; ++r) { T0[r] = 0.f; T1[r] = 0.f; }
    __builtin_amdgcn_s_setprio(1);
#pragma unroll
    for (int f = 0; f < 8; ++f) {
      const bf16x8 kf = *reinterpret_cast<const bf16x8*>(&Ksm[cur][koff[f]]);
      T0 = __builtin_amdgcn_mfma_f32_32x32x16_bf16(kf, qf[f], T0, 0, 0, 0);
    }
#pragma unroll
    for (int f = 0; f < 8; ++f) {
      const bf16x8 kf = *reinterpret_cast<const bf16x8*>(&Ksm[cur][koff[f] + 512]);
      T1 = __builtin_amdgcn_mfma_f32_32x32x16_bf16(kf, qf[f], T1, 0, 0, 0);
    }
    __builtin_amdgcn_s_setprio(0);

    if (sb == qi) {
      const int limit = (qsub << 5) + ql;
#pragma unroll
      for (int r = 0; r < 16; ++r) {
        const int kr = (r & 3) + ((r >> 2) << 3) + (hh << 2);
        if (kr > limit)      T0[r] = -1e30f;
        if (kr + 32 > limit) T1[r] = -1e30f;
      }
    }
    // pairwise tree max over 32 + VALU cross-half reduce
    float mx[8];
#pragma unroll
    for (int r = 0; r < 8; ++r)
      mx[r] = fmaxf(fmaxf(T0[2 * r], T0[2 * r + 1]), fmaxf(T1[2 * r], T1[2 * r + 1]));
#pragma unroll
    for (int r = 0; r < 4; ++r) mx[r] = fmaxf(mx[r], mx[r + 4]);
    mx[0] = fmaxf(mx[0], mx[2]);
    mx[1] = fmaxf(mx[1], mx[3]);
    const float mt = crosshalf_max(fmaxf(mx[0], mx[1]));

    if (__any(mt > m2 + 8.f)) {
      const float mnew = fmaxf(m2, mt);
      const float resc = exp2f(m2 - mnew);
      lsum *= resc;
#pragma unroll
      for (int r = 0; r < 16; ++r) {
        const int qr = (r & 3) + ((r >> 2) << 3) + (hh << 2);
        const float rr = __shfl(resc, qr);
#pragma unroll
        for (int dblk = 0; dblk < 4; ++dblk) o[dblk][r] *= rr;
      }
      m2 = mnew;
    }

    float ps = 0.f;
#pragma unroll
    for (int r = 0; r < 16; ++r) {
      const float p0 = exp2f(T0[r] - m2); T0[r] = p0; ps += p0;
      const float p1 = exp2f(T1[r] - m2); T1[r] = p1; ps += p1;
    }
    lsum += crosshalf_sum(ps);

    // ---- pack P (64 keys) -> 4 bf16 A-frags via permlane32_swap ----
    u32 pk[16];
#pragma unroll
    for (int i = 0; i < 8; ++i) {
      pk[i]     = cvt_pk_bf16(T0[2 * i], T0[2 * i + 1]);
      pk[8 + i] = cvt_pk_bf16(T1[2 * i], T1[2 * i + 1]);
    }
    pl32swap(pk[0], pk[2]);  pl32swap(pk[1], pk[3]);
    pl32swap(pk[4], pk[6]);  pl32swap(pk[5], pk[7]);
    pl32swap(pk[8], pk[10]); pl32swap(pk[9], pk[11]);
    pl32swap(pk[12], pk[14]); pl32swap(pk[13], pk[15]);
    bf16x8 a[4];
    a[0] = mk8(pk[0], pk[1], pk[2], pk[3]);
    a[1] = mk8(pk[4], pk[5], pk[6], pk[7]);
    a[2] = mk8(pk[8], pk[9], pk[10], pk[11]);
    a[3] = mk8(pk[12], pk[13], pk[14], pk[15]);

    __builtin_amdgcn_s_setprio(1);
#pragma unroll
    for (int dblk = 0; dblk < 4; ++dblk)
#pragma unroll
      for (int j = 0; j < 4; ++j) {
        const bf16x8 vb = *reinterpret_cast<const bf16x8*>(&Vsm[cur][voff[dblk][j]]);
        o[dblk] = __builtin_amdgcn_mfma_f32_32x32x16_bf16(a[j], vb, o[dblk], 0, 0, 0);
      }
    __builtin_amdgcn_s_setprio(0);
  }

  u16* Ob = Out + (size_t)(b * SEQ + q0 + (qsub << 5)) * HIDDEN_DIM + h * HEAD_DIM + ql;
#pragma unroll
  for (int r = 0; r < 16; ++r) {
    const int qr = (r & 3) + ((r >> 2) << 3) + (hh << 2);
    const float il = 1.0f / __shfl(lsum, qr);
    u16* rp = Ob + (size_t)qr * HIDDEN_DIM;
#pragma unroll
    for (int dblk = 0; dblk < 4; ++dblk)
      rp[dblk * 32] = f2bf(o[dblk][r] * il);
  }
}

// ---------------- launch ----------------
extern "C" void kernel_launch(void* const* d_in, const int* in_sizes, int n_in,
                              void* d_out, int out_size, void* d_ws, size_t ws_size,
                              hipStream_t stream)
{
  const float* hs   = (const float*)d_in[0];
  const float* wqkv = (const float*)d_in[1];
  const float* wo   = (const float*)d_in[2];
  float* out = (float*)d_out;
  char* ws = (char*)d_ws;
  size_t off = 0;
  auto alloc = [&](size_t bytes) -> void* {
    void* p = ws + off;
    off += (bytes + 255) & ~(size_t)255;
    return p;
  };
  u16* Xbf    = (u16*)alloc((size_t)ROWS * HIDDEN_DIM * 2);
  u16* Wqkvbf = (u16*)alloc((size_t)QKV_DIM * HIDDEN_DIM * 2);
  u16* Wobf   = (u16*)alloc((size_t)HIDDEN_DIM * HIDDEN_DIM * 2);
  u16* QKVbf  = (u16*)alloc((size_t)ROWS * QKV_DIM * 2);
  u16* Qbf    = (u16*)alloc((size_t)BSZ * N_HEADS * SEQ * HEAD_DIM * 2);
  u16* Kbf    = (u16*)alloc((size_t)BSZ * N_KV * SEQ * HEAD_DIM * 2);
  u16* Vtbf   = (u16*)alloc((size_t)BSZ * N_KV * SEQ * HEAD_DIM * 2);
  float* ctab = (float*)alloc((size_t)SEQ * 64 * 4);
  float* stab = (float*)alloc((size_t)SEQ * 64 * 4);
  u16* AOut   = (u16*)alloc((size_t)ROWS * HIDDEN_DIM * 2);
  if (off > ws_size) return;

  (void)hipFuncSetAttribute(reinterpret_cast<const void*>(&gemm256_k<0>),
                            hipFuncAttributeMaxDynamicSharedMemorySize, 131072);
  (void)hipFuncSetAttribute(reinterpret_cast<const void*>(&gemm256_k<1>),
                            hipFuncAttributeMaxDynamicSharedMemorySize, 131072);

  cast3_k<<<4096, 256, 0, stream>>>((const float4*)hs, (const float4*)wqkv, (const float4*)wo,
                                    (ushort4*)Xbf, (ushort4*)Wqkvbf, (ushort4*)Wobf,
                                    ROWS * HIDDEN_DIM / 4, QKV_DIM * HIDDEN_DIM / 4,
                                    HIDDEN_DIM * HIDDEN_DIM / 4);
  rope_tables_k<<<(SEQ * 64) / 256, 256, 0, stream>>>(ctab, stab);

  // GEMM1 split by output columns into two shape-optimal calls:
  //  cols [0,4096): 256x256 2-phase, 16x16 = 256 blocks = exactly 1 CU-round
  gemm256_k<0><<<(ROWS / 256) * (4096 / 256), 512, 131072, stream>>>(
      Xbf, Wqkvbf, (void*)QKVbf, ROWS, 4096, HIDDEN_DIM, QKV_DIM);
  //  cols [4096,6144): 128x128 m97, 32x16 = 512 blocks = exactly 1 round at 2/CU
  gemm_bt_k<0><<<(ROWS / 128) * (2048 / 128), 256, 0, stream>>>(
      Xbf, Wqkvbf + (size_t)4096 * HIDDEN_DIM, (void*)(QKVbf + 4096),
      ROWS, 2048, HIDDEN_DIM, QKV_DIM);

  rope_scatter_k<<<ROWS * ROPE_HEADS * 64 / 256, 256, 0, stream>>>(QKVbf, ctab, stab, Qbf, Kbf);
  vtrans_k<<<BSZ * N_KV * (SEQ / 64) * (HEAD_DIM / 64), 256, 0, stream>>>(QKVbf, Vtbf);
  attn_mfma_k<<<BSZ * N_KV * (SEQ / 64), 512, 0, stream>>>(Qbf, Kbf, Vtbf, AOut);
  gemm256_k<1><<<(ROWS / 256) * (HIDDEN_DIM / 256), 512, 131072, stream>>>(
      AOut, Wobf, (void*)out, ROWS, HIDDEN_DIM, HIDDEN_DIM, HIDDEN_DIM);
}

// Round 24
// 508.812 us; speedup vs baseline: 1.0147x; 1.0147x over previous
//
#include <hip/hip_runtime.h>
#include <stdint.h>

#define N_HEADS   32
#define N_KV      8
#define HEAD_DIM  128
#define HIDDEN_DIM 4096
#define BSZ       2
#define SEQ       2048
#define TOT_HEADS 48
#define QKV_DIM   6144   // TOT_HEADS * HEAD_DIM
#define ROWS      4096   // BSZ * SEQ
#define ROPE_HEADS 40    // Q + K heads (V not rope'd)

typedef __attribute__((ext_vector_type(4)))  float f32x4;
typedef __attribute__((ext_vector_type(16))) float f32x16;
typedef __attribute__((ext_vector_type(8)))  short bf16x8;
typedef unsigned short u16;
typedef unsigned int   u32;

#define AS1 __attribute__((address_space(1)))
#define AS3 __attribute__((address_space(3)))

static __device__ __forceinline__ float bf16f(u16 u) { return __uint_as_float(((u32)u) << 16); }
static __device__ __forceinline__ u16 f2bf(float f) {
  u32 x = __float_as_uint(f);
  x += 0x7fffu + ((x >> 16) & 1u);   // round-to-nearest-even
  return (u16)(x >> 16);
}
static __device__ __forceinline__ u32 cvt_pk_bf16(float lo, float hi) {
  u32 r;
  asm("v_cvt_pk_bf16_f32 %0, %1, %2" : "=v"(r) : "v"(lo), "v"(hi));
  return r;
}
static __device__ __forceinline__ bf16x8 mk8(u32 a, u32 b, u32 c, u32 d) {
  union { u32 u[4]; bf16x8 v; } x;
  x.u[0] = a; x.u[1] = b; x.u[2] = c; x.u[3] = d;
  return x.v;
}
// VALU cross-half swap: a' = {a.lo, b.lo}, b' = {a.hi, b.hi}  (T12).
static __device__ __forceinline__ void pl32swap(u32& a, u32& b) {
  asm("v_permlane32_swap_b32 %0, %1" : "+v"(a), "+v"(b));
}
// Cross-half reduce helpers: xb produced by an OPAQUE v_mov so the register
// coalescer cannot alias it with xa (R17 bug: coalesced copy -> swap v,v).
static __device__ __forceinline__ float crosshalf_max(float v) {
  u32 xa = __float_as_uint(v), xb;
  asm("v_mov_b32 %0, %1" : "=v"(xb) : "v"(xa));
  pl32swap(xa, xb);
  return fmaxf(__uint_as_float(xa), __uint_as_float(xb));
}
static __device__ __forceinline__ float crosshalf_sum(float v) {
  u32 xa = __float_as_uint(v), xb;
  asm("v_mov_b32 %0, %1" : "=v"(xb) : "v"(xa));
  pl32swap(xa, xb);
  return __uint_as_float(xa) + __uint_as_float(xb);
}

#define SBAR()  do { __builtin_amdgcn_sched_barrier(0); __builtin_amdgcn_s_barrier(); \
                     __builtin_amdgcn_sched_barrier(0); } while (0)
#define LGKM0() do { asm volatile("s_waitcnt lgkmcnt(0)" ::: "memory"); \
                     __builtin_amdgcn_sched_barrier(0); } while (0)

// ---------------- fused cast f32 -> bf16 for all three inputs ----------------
__global__ void cast3_k(const float4* __restrict__ a, const float4* __restrict__ b,
                        const float4* __restrict__ c,
                        ushort4* __restrict__ oa, ushort4* __restrict__ ob,
                        ushort4* __restrict__ oc, int na, int nb, int nc) {
  int i = blockIdx.x * blockDim.x + threadIdx.x;
  const int stride = gridDim.x * blockDim.x;
  const int tot = na + nb + nc;
  for (; i < tot; i += stride) {
    const float4* s; ushort4* d; int j = i;
    if (j < na)           { s = a; d = oa; }
    else if (j < na + nb) { s = b; d = ob; j -= na; }
    else                  { s = c; d = oc; j -= na + nb; }
    const float4 v = s[j];
    ushort4 o;
    o.x = f2bf(v.x); o.y = f2bf(v.y); o.z = f2bf(v.z); o.w = f2bf(v.w);
    d[j] = o;
  }
}

// ---------------- RoPE cos/sin tables (S x 64, half-dim) ----------------
__global__ void rope_tables_k(float* __restrict__ ctab, float* __restrict__ stab) {
  int t = blockIdx.x * blockDim.x + threadIdx.x;
  if (t >= SEQ * 64) return;
  int s = t >> 6, i = t & 63;
  float inv = powf(10000.0f, -(float)i / 64.0f);
  float ang = (float)s * inv;
  float sv, cv;
  sincosf(ang, &sv, &cv);
  ctab[t] = cv; stab[t] = sv;
}

// ---------------- 128x128 bf16 GEMM (m97 structure, measured 954 TF) ----------------
// ldc = C row stride (allows writing a column slab of a wider matrix).
template<int F32OUT>
__global__ __launch_bounds__(256, 2)
void gemm_bt_k(const u16* __restrict__ A, const u16* __restrict__ Bw,
               void* __restrict__ C, int M, int N, int K, int ldc)
{
  __shared__ uint4 smA[1024];
  __shared__ uint4 smB[1024];
  const int tid = threadIdx.x;
  const int nbx = N >> 7;
  const int bm = (blockIdx.x / nbx) << 7;
  const int bn = (blockIdx.x % nbx) << 7;
  const int lane = tid & 63;
  const int wave = tid >> 6;
  const int wm = (wave >> 1) << 6;
  const int wn = (wave & 1) << 6;
  const int fr = lane & 15;   // fragment row/col within 16
  const int fq = lane >> 4;   // 0..3

  f32x4 acc[4][4];
#pragma unroll
  for (int i = 0; i < 4; ++i)
#pragma unroll
    for (int j = 0; j < 4; ++j)
      acc[i][j] = {0.f, 0.f, 0.f, 0.f};

  const int gl_r = lane >> 3;                  // row-within-8 for this lane
  const int gl_c = (lane & 7) ^ gl_r;          // pre-swizzled global chunk

  for (int k0 = 0; k0 < K; k0 += 64) {
#pragma unroll
    for (int i = 0; i < 4; ++i) {
      const int rbase = (wave << 5) + (i << 3);      // wave-uniform row base
      const int row = rbase + gl_r;
      const u16* gA = A  + (size_t)(bm + row) * K + k0 + (gl_c << 3);
      const u16* gB = Bw + (size_t)(bn + row) * K + k0 + (gl_c << 3);
      __builtin_amdgcn_global_load_lds((const AS1 u32*)gA, (AS3 u32*)&smA[rbase << 3], 16, 0, 0);
      __builtin_amdgcn_global_load_lds((const AS1 u32*)gB, (AS3 u32*)&smB[rbase << 3], 16, 0, 0);
    }
    __syncthreads();
#pragma unroll
    for (int kk = 0; kk < 2; ++kk) {
      bf16x8 af[4], bfr[4];
      const int cc = (kk << 2) + fq;
#pragma unroll
      for (int m = 0; m < 4; ++m) {
        const int row = wm + (m << 4) + fr;
        af[m] = *reinterpret_cast<const bf16x8*>(&smA[(row << 3) + (cc ^ (row & 7))]);
      }
#pragma unroll
      for (int n = 0; n < 4; ++n) {
        const int row = wn + (n << 4) + fr;
        bfr[n] = *reinterpret_cast<const bf16x8*>(&smB[(row << 3) + (cc ^ (row & 7))]);
      }
#pragma unroll
      for (int m = 0; m < 4; ++m)
#pragma unroll
        for (int n = 0; n < 4; ++n)
          acc[m][n] = __builtin_amdgcn_mfma_f32_16x16x32_bf16(af[m], bfr[n], acc[m][n], 0, 0, 0);
    }
    __syncthreads();
  }

  // epilogue: D[row][col], row = fq*4+i (+m*16), col = fr (+n*16)
  const int col0 = bn + wn + fr;
#pragma unroll
  for (int m = 0; m < 4; ++m) {
#pragma unroll
    for (int i = 0; i < 4; ++i) {
      const int row = bm + wm + (m << 4) + (fq << 2) + i;
      if (F32OUT) {
        float* rp = reinterpret_cast<float*>(C) + (size_t)row * ldc + col0;
#pragma unroll
        for (int n = 0; n < 4; ++n) rp[n << 4] = acc[m][n][i];
      } else {
        u16* rp = reinterpret_cast<u16*>(C) + (size_t)row * ldc + col0;
#pragma unroll
        for (int n = 0; n < 4; ++n) rp[n << 4] = f2bf(acc[m][n][i]);
      }
    }
  }
}

// ---------------- 256x256 8-phase bf16 GEMM (m201 schedule, best measured) ----------------
// Wants grid = multiple of 256 blocks (1 block/CU rounds). ldc = C row stride.
template<int F32OUT>
__global__ __launch_bounds__(512, 2)
void gemm256_k(const u16* __restrict__ A, const u16* __restrict__ Bw,
               void* __restrict__ C, int M, int N, int K, int ldc)
{
  extern __shared__ uint4 lds[];
  uint4* LA = lds;          // [2 buf][256 rows][8 chunks] = 4096 uint4 = 64 KB
  uint4* LB = lds + 4096;   // same
  const int NT = K >> 6;
  const int tid  = threadIdx.x;
  const int lane = tid & 63;
  const int wave = tid >> 6;
  const int nbx = N >> 8;
  const int cpx = gridDim.x >> 3;
  const int wg  = (blockIdx.x & 7) * cpx + (blockIdx.x >> 3);   // XCD swizzle (nwg%8==0)
  const int bm = (wg / nbx) << 8;
  const int bn = (wg % nbx) << 8;

  const int wm = (wave >> 2) << 7;   // 0 / 128
  const int wn = (wave & 3) << 6;    // 0,64,128,192
  const int fr = lane & 15;
  const int fq = lane >> 4;
  const int s7 = fr & 7;

  const int rA  = (wave << 3) + (lane >> 3);
  const int c8e = (((lane & 7) ^ (lane >> 3)) << 3);   // element offset

  auto SA = [&](int t, int h, int buf) {
    uint4* d = LA + (buf << 11) + (h << 10) + (wave << 6);
    const u16* s = A + (size_t)(bm + (h << 7) + rA) * K + (t << 6) + c8e;
    __builtin_amdgcn_global_load_lds((const AS1 u32*)s, (AS3 u32*)d, 16, 0, 0);
    __builtin_amdgcn_global_load_lds((const AS1 u32*)(s + (size_t)64 * K), (AS3 u32*)(d + 512), 16, 0, 0);
  };
  auto SB = [&](int t, int h, int buf) {
    uint4* d = LB + (buf << 11) + (h << 10) + (wave << 6);
    const u16* s = Bw + (size_t)(bn + (h << 7) + rA) * K + (t << 6) + c8e;
    __builtin_amdgcn_global_load_lds((const AS1 u32*)s, (AS3 u32*)d, 16, 0, 0);
    __builtin_amdgcn_global_load_lds((const AS1 u32*)(s + (size_t)64 * K), (AS3 u32*)(d + 512), 16, 0, 0);
  };

  f32x4 acc[8][4];
#pragma unroll
  for (int m = 0; m < 8; ++m)
#pragma unroll
    for (int n = 0; n < 4; ++n)
      acc[m][n] = {0.f, 0.f, 0.f, 0.f};

  // prologue: tile0 all 4 halves, tile1 B-h0,B-h1,A-h0 (A-h1(1) staged at P1(0))
  SB(0, 0, 0); SB(0, 1, 0); SA(0, 0, 0); SA(0, 1, 0);
  SB(1, 0, 1); SB(1, 1, 1); SA(1, 0, 1);
  asm volatile("s_waitcnt vmcnt(6)" ::: "memory");
  SBAR();

  bf16x8 Af[4][2], B0[2][2], B1[2][2];

#pragma unroll 1
  for (int t = 0; t < NT; ++t) {
    const int buf  = t & 1;
    const int base = buf << 11;
    const int abase = base + ((wm + fr) << 3);
    const int bbase = base + ((wn + fr) << 3);

    // ---- P1: read A-lo + B-lo; stage A-h1(t+1); MFMA mlo x nlo ----
#pragma unroll
    for (int m = 0; m < 4; ++m)
#pragma unroll
      for (int kk = 0; kk < 2; ++kk)
        Af[m][kk] = *reinterpret_cast<const bf16x8*>(&LA[abase + m * 128 + (((kk << 2) + fq) ^ s7)]);
#pragma unroll
    for (int n = 0; n < 2; ++n)
#pragma unroll
      for (int kk = 0; kk < 2; ++kk)
        B0[n][kk] = *reinterpret_cast<const bf16x8*>(&LB[bbase + n * 128 + (((kk << 2) + fq) ^ s7)]);
    if (t + 1 < NT) SA(t + 1, 1, buf ^ 1);
    SBAR();
    LGKM0();
    __builtin_amdgcn_s_setprio(1);
#pragma unroll
    for (int m = 0; m < 4; ++m)
#pragma unroll
      for (int n = 0; n < 2; ++n)
#pragma unroll
        for (int kk = 0; kk < 2; ++kk)
          acc[m][n] = __builtin_amdgcn_mfma_f32_16x16x32_bf16(Af[m][kk], B0[n][kk], acc[m][n], 0, 0, 0);
    __builtin_amdgcn_s_setprio(0);
    SBAR();

    // ---- P2: read B-hi; MFMA mlo x nhi ----
#pragma unroll
    for (int n = 0; n < 2; ++n)
#pragma unroll
      for (int kk = 0; kk < 2; ++kk)
        B1[n][kk] = *reinterpret_cast<const bf16x8*>(&LB[bbase + (2 + n) * 128 + (((kk << 2) + fq) ^ s7)]);
    SBAR();
    LGKM0();
    __builtin_amdgcn_s_setprio(1);
#pragma unroll
    for (int m = 0; m < 4; ++m)
#pragma unroll
      for (int n = 0; n < 2; ++n)
#pragma unroll
        for (int kk = 0; kk < 2; ++kk)
          acc[m][2 + n] = __builtin_amdgcn_mfma_f32_16x16x32_bf16(Af[m][kk], B1[n][kk], acc[m][2 + n], 0, 0, 0);
    __builtin_amdgcn_s_setprio(0);
    SBAR();

    // ---- P3: read A-hi; stage B-h0(t+2); MFMA mhi x nhi ----
#pragma unroll
    for (int m = 0; m < 4; ++m)
#pragma unroll
      for (int kk = 0; kk < 2; ++kk)
        Af[m][kk] = *reinterpret_cast<const bf16x8*>(&LA[abase + 512 + m * 128 + (((kk << 2) + fq) ^ s7)]);
    if (t + 2 < NT) SB(t + 2, 0, buf);
    SBAR();
    LGKM0();
    __builtin_amdgcn_s_setprio(1);
#pragma unroll
    for (int m = 0; m < 4; ++m)
#pragma unroll
      for (int n = 0; n < 2; ++n)
#pragma unroll
        for (int kk = 0; kk < 2; ++kk)
          acc[4 + m][2 + n] = __builtin_amdgcn_mfma_f32_16x16x32_bf16(Af[m][kk], B1[n][kk], acc[4 + m][2 + n], 0, 0, 0);
    __builtin_amdgcn_s_setprio(0);
    SBAR();

    // ---- P4: stage B-h1(t+2)+A-h0(t+2); MFMA mhi x nlo; GATE ----
    if (t + 2 < NT) { SB(t + 2, 1, buf); SA(t + 2, 0, buf); }
    __builtin_amdgcn_s_setprio(1);
#pragma unroll
    for (int m = 0; m < 4; ++m)
#pragma unroll
      for (int n = 0; n < 2; ++n)
#pragma unroll
        for (int kk = 0; kk < 2; ++kk)
          acc[4 + m][n] = __builtin_amdgcn_mfma_f32_16x16x32_bf16(Af[m][kk], B0[n][kk], acc[4 + m][n], 0, 0, 0);
    __builtin_amdgcn_s_setprio(0);
    if (t < NT - 2)       { asm volatile("s_waitcnt vmcnt(6)" ::: "memory"); }
    else if (t == NT - 2) { asm volatile("s_waitcnt vmcnt(0)" ::: "memory"); }
    SBAR();
  }

  // epilogue: D row = bm+wm+m*16+fq*4+i, col = bn+wn+n*16+fr
  const int col0 = bn + wn + fr;
#pragma unroll
  for (int m = 0; m < 8; ++m) {
#pragma unroll
    for (int i = 0; i < 4; ++i) {
      const int row = bm + wm + (m << 4) + (fq << 2) + i;
      if (F32OUT) {
        float* rp = reinterpret_cast<float*>(C) + (size_t)row * ldc + col0;
#pragma unroll
        for (int n = 0; n < 4; ++n) rp[n << 4] = acc[m][n][i];
      } else {
        u16* rp = reinterpret_cast<u16*>(C) + (size_t)row * ldc + col0;
#pragma unroll
        for (int n = 0; n < 4; ++n) rp[n << 4] = f2bf(acc[m][n][i]);
      }
    }
  }
}

// ---------------- RoPE + scatter Q,K heads -> Q(B,H,S,D) K(B,KV,S,D) ----------------
// Q heads pre-scaled by 1/sqrt(128)*log2(e): scores leave QK^T in log2 domain.
__global__ void rope_scatter_k(const u16* __restrict__ QKV,
                               const float* __restrict__ ctab, const float* __restrict__ stab,
                               u16* __restrict__ Qo, u16* __restrict__ Ko)
{
  const int t = blockIdx.x * blockDim.x + threadIdx.x;  // ROWS*40*64 threads
  const int d = t & 63;
  const int hh = (t >> 6) % ROPE_HEADS;
  const int row = t / (64 * ROPE_HEADS);
  const int b = row >> 11, sq = row & (SEQ - 1);
  const u16* src = QKV + (size_t)row * QKV_DIM + hh * HEAD_DIM;
  const float x1 = bf16f(src[d]);
  const float x2 = bf16f(src[d + 64]);
  const float c = ctab[(sq << 6) + d], sn = stab[(sq << 6) + d];
  float y1 = x1 * c - x2 * sn;
  float y2 = x2 * c + x1 * sn;
  u16* dst;
  if (hh < N_HEADS) {
    const float SC2 = 0.1275170747f;   // (1/sqrt(128)) * log2(e)
    y1 *= SC2; y2 *= SC2;
    dst = Qo + ((size_t)(b * N_HEADS + hh) * SEQ + sq) * HEAD_DIM;
  } else {
    dst = Ko + ((size_t)(b * N_KV + (hh - N_HEADS)) * SEQ + sq) * HEAD_DIM;
  }
  dst[d] = f2bf(y1);
  dst[d + 64] = f2bf(y2);
}

// ---------------- V transpose: QKV cols [5120,6144) -> Vt[b][kv][d][s] ----------------
__global__ __launch_bounds__(256)
void vtrans_k(const u16* __restrict__ QKV, u16* __restrict__ Vt)
{
  __shared__ u16 tile[64][72];
  const int idx = blockIdx.x;           // dt(1) | st(5) | kv(3) | b(1)
  const int dt = idx & 1;
  const int st = (idx >> 1) & 31;
  const int kv = (idx >> 6) & 7;
  const int b  = idx >> 9;
  const int tid = threadIdx.x;
  const int s0 = st << 6, d0 = dt << 6;
  const int rl = tid >> 3, cc8 = (tid & 7) << 3;
#pragma unroll
  for (int p = 0; p < 2; ++p) {
    const int sl = rl + (p << 5);
    const u16* src = QKV + (size_t)(b * SEQ + s0 + sl) * QKV_DIM
                   + (N_HEADS + N_KV + kv) * HEAD_DIM + d0 + cc8;
    *reinterpret_cast<uint4*>(&tile[sl][cc8]) = *reinterpret_cast<const uint4*>(src);
  }
  __syncthreads();
#pragma unroll
  for (int p = 0; p < 2; ++p) {
    const int dl = rl + (p << 5);
    u16 tmp[8];
#pragma unroll
    for (int k2 = 0; k2 < 8; ++k2) tmp[k2] = tile[cc8 + k2][dl];
    u16* dst = Vt + ((size_t)(b * N_KV + kv) * HEAD_DIM + d0 + dl) * SEQ + s0 + cc8;
    *reinterpret_cast<uint4*>(dst) = *reinterpret_cast<const uint4*>(tmp);
  }
}

// ---------------- MFMA flash attention (causal GQA, KVBLK=64) ----------------
// R22 version (best measured): KVBLK=64, launch_bounds(512,2), V rows 8 chunks
// with rotation swizzle slot=(c+d)&7 (inverse on stage), permlane pack/reduce.
__global__ __launch_bounds__(512, 2)
void attn_mfma_k(const u16* __restrict__ Q, const u16* __restrict__ K,
                 const u16* __restrict__ Vt, u16* __restrict__ Out)
{
  __shared__ uint4 Ksm[2][1024];
  __shared__ uint4 Vsm[2][1024];
  const int tid  = threadIdx.x;
  const int lane = tid & 63;
  const int w    = tid >> 6;
  const int idx  = blockIdx.x;                    // qrev(5) | b(1) | kvh(3)
  const int kvh  = idx & 7;                       // XCD-pinned KV
  const int b    = (idx >> 3) & 1;
  const int qi   = 31 - (idx >> 4);               // heaviest q-tiles first
  const int q0   = qi << 6;                       // 64-row q-tile base
  const int head = w & 3;
  const int qsub = w >> 2;
  const int h    = (kvh << 2) + head;

  const int ql = lane & 31;
  const int hh = lane >> 5;

  const u16* Qh = Q  + (size_t)(b * N_HEADS + h) * SEQ * HEAD_DIM;
  const u16* Kb = K  + (size_t)(b * N_KV + kvh) * SEQ * HEAD_DIM;
  const u16* Vb = Vt + (size_t)(b * N_KV + kvh) * HEAD_DIM * SEQ;

  int koff[8];
#pragma unroll
  for (int f = 0; f < 8; ++f) koff[f] = (ql << 4) + (((f << 1) + hh) ^ (ql & 15));
  // V read offsets: row d = dblk*32+ql (8 chunks/row), slot = (2j+hh+d)&7 = (2j+hh+ql)&7
  int voff[4][4];
#pragma unroll
  for (int dblk = 0; dblk < 4; ++dblk)
#pragma unroll
    for (int j = 0; j < 4; ++j)
      voff[dblk][j] = ((((dblk << 5) + ql) << 3)) + (((j << 1) + hh + ql) & 7);

  auto stage = [&](int buf, int ks) {
#pragma unroll
    for (int p = 0; p < 2; ++p) {           // K: 64 rows x 16 chunks = 1024
      const int base = (p << 9) + (w << 6);
      const int sl2 = base + lane;
      const int row = sl2 >> 4, cs = sl2 & 15;
      const int g = cs ^ (row & 15);
      const u16* src = Kb + (size_t)(ks + row) * HEAD_DIM + (g << 3);
      __builtin_amdgcn_global_load_lds((const AS1 u32*)src, (AS3 u32*)&Ksm[buf][base], 16, 0, 0);
    }
#pragma unroll
    for (int p = 0; p < 2; ++p) {           // V: 128 rows x 8 chunks = 1024
      const int base = (p << 9) + (w << 6);
      const int sl2 = base + lane;
      const int d = sl2 >> 3, cs = sl2 & 7;
      const int g = (cs - d) & 7;           // inverse of read rotation
      const u16* src = Vb + (size_t)d * SEQ + ks + (g << 3);
      __builtin_amdgcn_global_load_lds((const AS1 u32*)src, (AS3 u32*)&Vsm[buf][base], 16, 0, 0);
    }
  };

  bf16x8 qf[8];
#pragma unroll
  for (int f = 0; f < 8; ++f)
    qf[f] = *reinterpret_cast<const bf16x8*>(Qh + (size_t)(q0 + (qsub << 5) + ql) * HEAD_DIM
                                             + 16 * f + 8 * hh);

  f32x16 o[4];
#pragma unroll
  for (int dblk = 0; dblk < 4; ++dblk)
#pragma unroll
    for (int r = 0; r < 16; ++r) o[dblk][r] = 0.f;
  float m2 = -1e30f, lsum = 0.f;

  stage(0, 0);

#pragma unroll 1
  for (int sb = 0; sb <= qi; ++sb) {
    const int cur = sb & 1;
    __syncthreads();          // drains stage(sb) (vmcnt 0); prev compute done
    if (sb < qi) stage(cur ^ 1, (sb + 1) << 6);   // prefetch under compute

    f32x16 T0, T1;
#pragma unroll
    for (int r = 0; r < 16; ++r) { T0[r] = 0.f; T1[r] = 0.f; }
    __builtin_amdgcn_s_setprio(1);
#pragma unroll
    for (int f = 0; f < 8; ++f) {
      const bf16x8 kf = *reinterpret_cast<const bf16x8*>(&Ksm[cur][koff[f]]);
      T0 = __builtin_amdgcn_mfma_f32_32x32x16_bf16(kf, qf[f], T0, 0, 0, 0);
    }
#pragma unroll
    for (int f = 0; f < 8; ++f) {
      const bf16x8 kf = *reinterpret_cast<const bf16x8*>(&Ksm[cur][koff[f] + 512]);
      T1 = __builtin_amdgcn_mfma_f32_32x32x16_bf16(kf, qf[f], T1, 0, 0, 0);
    }
    __builtin_amdgcn_s_setprio(0);

    if (sb == qi) {
      const int limit = (qsub << 5) + ql;
#pragma unroll
      for (int r = 0; r < 16; ++r) {
        const int kr = (r & 3) + ((r >> 2) << 3) + (hh << 2);
        if (kr > limit)      T0[r] = -1e30f;
        if (kr + 32 > limit) T1[r] = -1e30f;
      }
    }
    // pairwise tree max over 32 + VALU cross-half reduce
    float mx[8];
#pragma unroll
    for (int r = 0; r < 8; ++r)
      mx[r] = fmaxf(fmaxf(T0[2 * r], T0[2 * r + 1]), fmaxf(T1[2 * r], T1[2 * r + 1]));
#pragma unroll
    for (int r = 0; r < 4; ++r) mx[r] = fmaxf(mx[r], mx[r + 4]);
    mx[0] = fmaxf(mx[0], mx[2]);
    mx[1] = fmaxf(mx[1], mx[3]);
    const float mt = crosshalf_max(fmaxf(mx[0], mx[1]));

    if (__any(mt > m2 + 8.f)) {
      const float mnew = fmaxf(m2, mt);
      const float resc = exp2f(m2 - mnew);
      lsum *= resc;
#pragma unroll
      for (int r = 0; r < 16; ++r) {
        const int qr = (r & 3) + ((r >> 2) << 3) + (hh << 2);
        const float rr = __shfl(resc, qr);
#pragma unroll
        for (int dblk = 0; dblk < 4; ++dblk) o[dblk][r] *= rr;
      }
      m2 = mnew;
    }

    float ps = 0.f;
#pragma unroll
    for (int r = 0; r < 16; ++r) {
      const float p0 = exp2f(T0[r] - m2); T0[r] = p0; ps += p0;
      const float p1 = exp2f(T1[r] - m2); T1[r] = p1; ps += p1;
    }
    lsum += crosshalf_sum(ps);

    // ---- pack P (64 keys) -> 4 bf16 A-frags via permlane32_swap ----
    u32 pk[16];
#pragma unroll
    for (int i = 0; i < 8; ++i) {
      pk[i]     = cvt_pk_bf16(T0[2 * i], T0[2 * i + 1]);
      pk[8 + i] = cvt_pk_bf16(T1[2 * i], T1[2 * i + 1]);
    }
    pl32swap(pk[0], pk[2]);  pl32swap(pk[1], pk[3]);
    pl32swap(pk[4], pk[6]);  pl32swap(pk[5], pk[7]);
    pl32swap(pk[8], pk[10]); pl32swap(pk[9], pk[11]);
    pl32swap(pk[12], pk[14]); pl32swap(pk[13], pk[15]);
    bf16x8 a[4];
    a[0] = mk8(pk[0], pk[1], pk[2], pk[3]);
    a[1] = mk8(pk[4], pk[5], pk[6], pk[7]);
    a[2] = mk8(pk[8], pk[9], pk[10], pk[11]);
    a[3] = mk8(pk[12], pk[13], pk[14], pk[15]);

    __builtin_amdgcn_s_setprio(1);
#pragma unroll
    for (int dblk = 0; dblk < 4; ++dblk)
#pragma unroll
      for (int j = 0; j < 4; ++j) {
        const bf16x8 vb = *reinterpret_cast<const bf16x8*>(&Vsm[cur][voff[dblk][j]]);
        o[dblk] = __builtin_amdgcn_mfma_f32_32x32x16_bf16(a[j], vb, o[dblk], 0, 0, 0);
      }
    __builtin_amdgcn_s_setprio(0);
  }

  u16* Ob = Out + (size_t)(b * SEQ + q0 + (qsub << 5)) * HIDDEN_DIM + h * HEAD_DIM + ql;
#pragma unroll
  for (int r = 0; r < 16; ++r) {
    const int qr = (r & 3) + ((r >> 2) << 3) + (hh << 2);
    const float il = 1.0f / __shfl(lsum, qr);
    u16* rp = Ob + (size_t)qr * HIDDEN_DIM;
#pragma unroll
    for (int dblk = 0; dblk < 4; ++dblk)
      rp[dblk * 32] = f2bf(o[dblk][r] * il);
  }
}

// ---------------- launch ----------------
extern "C" void kernel_launch(void* const* d_in, const int* in_sizes, int n_in,
                              void* d_out, int out_size, void* d_ws, size_t ws_size,
                              hipStream_t stream)
{
  const float* hs   = (const float*)d_in[0];
  const float* wqkv = (const float*)d_in[1];
  const float* wo   = (const float*)d_in[2];
  float* out = (float*)d_out;
  char* ws = (char*)d_ws;
  size_t off = 0;
  auto alloc = [&](size_t bytes) -> void* {
    void* p = ws + off;
    off += (bytes + 255) & ~(size_t)255;
    return p;
  };
  u16* Xbf    = (u16*)alloc((size_t)ROWS * HIDDEN_DIM * 2);
  u16* Wqkvbf = (u16*)alloc((size_t)QKV_DIM * HIDDEN_DIM * 2);
  u16* Wobf   = (u16*)alloc((size_t)HIDDEN_DIM * HIDDEN_DIM * 2);
  u16* QKVbf  = (u16*)alloc((size_t)ROWS * QKV_DIM * 2);
  u16* Qbf    = (u16*)alloc((size_t)BSZ * N_HEADS * SEQ * HEAD_DIM * 2);
  u16* Kbf    = (u16*)alloc((size_t)BSZ * N_KV * SEQ * HEAD_DIM * 2);
  u16* Vtbf   = (u16*)alloc((size_t)BSZ * N_KV * SEQ * HEAD_DIM * 2);
  float* ctab = (float*)alloc((size_t)SEQ * 64 * 4);
  float* stab = (float*)alloc((size_t)SEQ * 64 * 4);
  u16* AOut   = (u16*)alloc((size_t)ROWS * HIDDEN_DIM * 2);
  if (off > ws_size) return;

  (void)hipFuncSetAttribute(reinterpret_cast<const void*>(&gemm256_k<0>),
                            hipFuncAttributeMaxDynamicSharedMemorySize, 131072);
  (void)hipFuncSetAttribute(reinterpret_cast<const void*>(&gemm256_k<1>),
                            hipFuncAttributeMaxDynamicSharedMemorySize, 131072);

  cast3_k<<<4096, 256, 0, stream>>>((const float4*)hs, (const float4*)wqkv, (const float4*)wo,
                                    (ushort4*)Xbf, (ushort4*)Wqkvbf, (ushort4*)Wobf,
                                    ROWS * HIDDEN_DIM / 4, QKV_DIM * HIDDEN_DIM / 4,
                                    HIDDEN_DIM * HIDDEN_DIM / 4);
  rope_tables_k<<<(SEQ * 64) / 256, 256, 0, stream>>>(ctab, stab);

  // GEMM1 split by output columns into two shape-optimal calls:
  //  cols [0,4096): 256x256 8-phase, 16x16 = 256 blocks = exactly 1 CU-round
  gemm256_k<0><<<(ROWS / 256) * (4096 / 256), 512, 131072, stream>>>(
      Xbf, Wqkvbf, (void*)QKVbf, ROWS, 4096, HIDDEN_DIM, QKV_DIM);
  //  cols [4096,6144): 128x128 m97, 32x16 = 512 blocks = exactly 1 round at 2/CU
  gemm_bt_k<0><<<(ROWS / 128) * (2048 / 128), 256, 0, stream>>>(
      Xbf, Wqkvbf + (size_t)4096 * HIDDEN_DIM, (void*)(QKVbf + 4096),
      ROWS, 2048, HIDDEN_DIM, QKV_DIM);

  rope_scatter_k<<<ROWS * ROPE_HEADS * 64 / 256, 256, 0, stream>>>(QKVbf, ctab, stab, Qbf, Kbf);
  vtrans_k<<<BSZ * N_KV * (SEQ / 64) * (HEAD_DIM / 64), 256, 0, stream>>>(QKVbf, Vtbf);
  attn_mfma_k<<<BSZ * N_KV * (SEQ / 64), 512, 0, stream>>>(Qbf, Kbf, Vtbf, AOut);
  gemm256_k<1><<<(ROWS / 256) * (HIDDEN_DIM / 256), 512, 131072, stream>>>(
      AOut, Wobf, (void*)out, ROWS, HIDDEN_DIM, HIDDEN_DIM, HIDDEN_DIM);
}

// Round 25
// 506.080 us; speedup vs baseline: 1.0202x; 1.0054x over previous
//
#include <hip/hip_runtime.h>
#include <stdint.h>

#define N_HEADS   32
#define N_KV      8
#define HEAD_DIM  128
#define HIDDEN_DIM 4096
#define BSZ       2
#define SEQ       2048
#define TOT_HEADS 48
#define QKV_DIM   6144   // TOT_HEADS * HEAD_DIM
#define ROWS      4096   // BSZ * SEQ
#define ROPE_HEADS 40    // Q + K heads (V not rope'd)

typedef __attribute__((ext_vector_type(4)))  float f32x4;
typedef __attribute__((ext_vector_type(16))) float f32x16;
typedef __attribute__((ext_vector_type(8)))  short bf16x8;
typedef unsigned short u16;
typedef unsigned int   u32;

#define AS1 __attribute__((address_space(1)))
#define AS3 __attribute__((address_space(3)))

static __device__ __forceinline__ float bf16f(u16 u) { return __uint_as_float(((u32)u) << 16); }
static __device__ __forceinline__ u16 f2bf(float f) {
  u32 x = __float_as_uint(f);
  x += 0x7fffu + ((x >> 16) & 1u);   // round-to-nearest-even
  return (u16)(x >> 16);
}
static __device__ __forceinline__ u32 cvt_pk_bf16(float lo, float hi) {
  u32 r;
  asm("v_cvt_pk_bf16_f32 %0, %1, %2" : "=v"(r) : "v"(lo), "v"(hi));
  return r;
}
static __device__ __forceinline__ bf16x8 mk8(u32 a, u32 b, u32 c, u32 d) {
  union { u32 u[4]; bf16x8 v; } x;
  x.u[0] = a; x.u[1] = b; x.u[2] = c; x.u[3] = d;
  return x.v;
}
// VALU cross-half swap: a' = {a.lo, b.lo}, b' = {a.hi, b.hi}  (T12).
static __device__ __forceinline__ void pl32swap(u32& a, u32& b) {
  asm("v_permlane32_swap_b32 %0, %1" : "+v"(a), "+v"(b));
}
// Cross-half reduce helpers: xb produced by an OPAQUE v_mov so the register
// coalescer cannot alias it with xa (R17 bug: coalesced copy -> swap v,v).
static __device__ __forceinline__ float crosshalf_max(float v) {
  u32 xa = __float_as_uint(v), xb;
  asm("v_mov_b32 %0, %1" : "=v"(xb) : "v"(xa));
  pl32swap(xa, xb);
  return fmaxf(__uint_as_float(xa), __uint_as_float(xb));
}
static __device__ __forceinline__ float crosshalf_sum(float v) {
  u32 xa = __float_as_uint(v), xb;
  asm("v_mov_b32 %0, %1" : "=v"(xb) : "v"(xa));
  pl32swap(xa, xb);
  return __uint_as_float(xa) + __uint_as_float(xb);
}

#define SBAR()  do { __builtin_amdgcn_sched_barrier(0); __builtin_amdgcn_s_barrier(); \
                     __builtin_amdgcn_sched_barrier(0); } while (0)
#define LGKM0() do { asm volatile("s_waitcnt lgkmcnt(0)" ::: "memory"); \
                     __builtin_amdgcn_sched_barrier(0); } while (0)

// ---------------- prep: fused f32->bf16 casts + RoPE tables (one launch) ----------------
// blocks [0,4096): grid-stride cast of all three inputs (stride fixed at 4096*256)
// blocks [4096,4608): cos/sin tables (S x 64 half-dim)
__global__ __launch_bounds__(256)
void prep_k(const float4* __restrict__ a, const float4* __restrict__ b,
            const float4* __restrict__ c,
            ushort4* __restrict__ oa, ushort4* __restrict__ ob,
            ushort4* __restrict__ oc, int na, int nb, int nc,
            float* __restrict__ ctab, float* __restrict__ stab) {
  const int blk = blockIdx.x;
  if (blk < 4096) {
    int i = blk * 256 + threadIdx.x;
    const int stride = 4096 * 256;
    const int tot = na + nb + nc;
    for (; i < tot; i += stride) {
      const float4* s; ushort4* d; int j = i;
      if (j < na)           { s = a; d = oa; }
      else if (j < na + nb) { s = b; d = ob; j -= na; }
      else                  { s = c; d = oc; j -= na + nb; }
      const float4 v = s[j];
      ushort4 o;
      o.x = f2bf(v.x); o.y = f2bf(v.y); o.z = f2bf(v.z); o.w = f2bf(v.w);
      d[j] = o;
    }
  } else {
    const int t = (blk - 4096) * 256 + threadIdx.x;
    if (t >= SEQ * 64) return;
    const int s = t >> 6, i = t & 63;
    const float inv = powf(10000.0f, -(float)i / 64.0f);
    const float ang = (float)s * inv;
    float sv, cv;
    sincosf(ang, &sv, &cv);
    ctab[t] = cv; stab[t] = sv;
  }
}

// ---------------- 128x128 bf16 GEMM (m97 structure, measured 954 TF) ----------------
// ldc = C row stride (allows writing a column slab of a wider matrix).
template<int F32OUT>
__global__ __launch_bounds__(256, 2)
void gemm_bt_k(const u16* __restrict__ A, const u16* __restrict__ Bw,
               void* __restrict__ C, int M, int N, int K, int ldc)
{
  __shared__ uint4 smA[1024];
  __shared__ uint4 smB[1024];
  const int tid = threadIdx.x;
  const int nbx = N >> 7;
  const int bm = (blockIdx.x / nbx) << 7;
  const int bn = (blockIdx.x % nbx) << 7;
  const int lane = tid & 63;
  const int wave = tid >> 6;
  const int wm = (wave >> 1) << 6;
  const int wn = (wave & 1) << 6;
  const int fr = lane & 15;   // fragment row/col within 16
  const int fq = lane >> 4;   // 0..3

  f32x4 acc[4][4];
#pragma unroll
  for (int i = 0; i < 4; ++i)
#pragma unroll
    for (int j = 0; j < 4; ++j)
      acc[i][j] = {0.f, 0.f, 0.f, 0.f};

  const int gl_r = lane >> 3;                  // row-within-8 for this lane
  const int gl_c = (lane & 7) ^ gl_r;          // pre-swizzled global chunk

  for (int k0 = 0; k0 < K; k0 += 64) {
#pragma unroll
    for (int i = 0; i < 4; ++i) {
      const int rbase = (wave << 5) + (i << 3);      // wave-uniform row base
      const int row = rbase + gl_r;
      const u16* gA = A  + (size_t)(bm + row) * K + k0 + (gl_c << 3);
      const u16* gB = Bw + (size_t)(bn + row) * K + k0 + (gl_c << 3);
      __builtin_amdgcn_global_load_lds((const AS1 u32*)gA, (AS3 u32*)&smA[rbase << 3], 16, 0, 0);
      __builtin_amdgcn_global_load_lds((const AS1 u32*)gB, (AS3 u32*)&smB[rbase << 3], 16, 0, 0);
    }
    __syncthreads();
#pragma unroll
    for (int kk = 0; kk < 2; ++kk) {
      bf16x8 af[4], bfr[4];
      const int cc = (kk << 2) + fq;
#pragma unroll
      for (int m = 0; m < 4; ++m) {
        const int row = wm + (m << 4) + fr;
        af[m] = *reinterpret_cast<const bf16x8*>(&smA[(row << 3) + (cc ^ (row & 7))]);
      }
#pragma unroll
      for (int n = 0; n < 4; ++n) {
        const int row = wn + (n << 4) + fr;
        bfr[n] = *reinterpret_cast<const bf16x8*>(&smB[(row << 3) + (cc ^ (row & 7))]);
      }
#pragma unroll
      for (int m = 0; m < 4; ++m)
#pragma unroll
        for (int n = 0; n < 4; ++n)
          acc[m][n] = __builtin_amdgcn_mfma_f32_16x16x32_bf16(af[m], bfr[n], acc[m][n], 0, 0, 0);
    }
    __syncthreads();
  }

  // epilogue: D[row][col], row = fq*4+i (+m*16), col = fr (+n*16)
  const int col0 = bn + wn + fr;
#pragma unroll
  for (int m = 0; m < 4; ++m) {
#pragma unroll
    for (int i = 0; i < 4; ++i) {
      const int row = bm + wm + (m << 4) + (fq << 2) + i;
      if (F32OUT) {
        float* rp = reinterpret_cast<float*>(C) + (size_t)row * ldc + col0;
#pragma unroll
        for (int n = 0; n < 4; ++n) rp[n << 4] = acc[m][n][i];
      } else {
        u16* rp = reinterpret_cast<u16*>(C) + (size_t)row * ldc + col0;
#pragma unroll
        for (int n = 0; n < 4; ++n) rp[n << 4] = f2bf(acc[m][n][i]);
      }
    }
  }
}

// ---------------- 256x256 8-phase bf16 GEMM (m201 schedule, best measured) ----------------
// Wants grid = multiple of 256 blocks (1 block/CU rounds). ldc = C row stride.
template<int F32OUT>
__global__ __launch_bounds__(512, 2)
void gemm256_k(const u16* __restrict__ A, const u16* __restrict__ Bw,
               void* __restrict__ C, int M, int N, int K, int ldc)
{
  extern __shared__ uint4 lds[];
  uint4* LA = lds;          // [2 buf][256 rows][8 chunks] = 4096 uint4 = 64 KB
  uint4* LB = lds + 4096;   // same
  const int NT = K >> 6;
  const int tid  = threadIdx.x;
  const int lane = tid & 63;
  const int wave = tid >> 6;
  const int nbx = N >> 8;
  const int cpx = gridDim.x >> 3;
  const int wg  = (blockIdx.x & 7) * cpx + (blockIdx.x >> 3);   // XCD swizzle (nwg%8==0)
  const int bm = (wg / nbx) << 8;
  const int bn = (wg % nbx) << 8;

  const int wm = (wave >> 2) << 7;   // 0 / 128
  const int wn = (wave & 3) << 6;    // 0,64,128,192
  const int fr = lane & 15;
  const int fq = lane >> 4;
  const int s7 = fr & 7;

  const int rA  = (wave << 3) + (lane >> 3);
  const int c8e = (((lane & 7) ^ (lane >> 3)) << 3);   // element offset

  auto SA = [&](int t, int h, int buf) {
    uint4* d = LA + (buf << 11) + (h << 10) + (wave << 6);
    const u16* s = A + (size_t)(bm + (h << 7) + rA) * K + (t << 6) + c8e;
    __builtin_amdgcn_global_load_lds((const AS1 u32*)s, (AS3 u32*)d, 16, 0, 0);
    __builtin_amdgcn_global_load_lds((const AS1 u32*)(s + (size_t)64 * K), (AS3 u32*)(d + 512), 16, 0, 0);
  };
  auto SB = [&](int t, int h, int buf) {
    uint4* d = LB + (buf << 11) + (h << 10) + (wave << 6);
    const u16* s = Bw + (size_t)(bn + (h << 7) + rA) * K + (t << 6) + c8e;
    __builtin_amdgcn_global_load_lds((const AS1 u32*)s, (AS3 u32*)d, 16, 0, 0);
    __builtin_amdgcn_global_load_lds((const AS1 u32*)(s + (size_t)64 * K), (AS3 u32*)(d + 512), 16, 0, 0);
  };

  f32x4 acc[8][4];
#pragma unroll
  for (int m = 0; m < 8; ++m)
#pragma unroll
    for (int n = 0; n < 4; ++n)
      acc[m][n] = {0.f, 0.f, 0.f, 0.f};

  // prologue: tile0 all 4 halves, tile1 B-h0,B-h1,A-h0 (A-h1(1) staged at P1(0))
  SB(0, 0, 0); SB(0, 1, 0); SA(0, 0, 0); SA(0, 1, 0);
  SB(1, 0, 1); SB(1, 1, 1); SA(1, 0, 1);
  asm volatile("s_waitcnt vmcnt(6)" ::: "memory");
  SBAR();

  bf16x8 Af[4][2], B0[2][2], B1[2][2];

#pragma unroll 1
  for (int t = 0; t < NT; ++t) {
    const int buf  = t & 1;
    const int base = buf << 11;
    const int abase = base + ((wm + fr) << 3);
    const int bbase = base + ((wn + fr) << 3);

    // ---- P1: read A-lo + B-lo; stage A-h1(t+1); MFMA mlo x nlo ----
#pragma unroll
    for (int m = 0; m < 4; ++m)
#pragma unroll
      for (int kk = 0; kk < 2; ++kk)
        Af[m][kk] = *reinterpret_cast<const bf16x8*>(&LA[abase + m * 128 + (((kk << 2) + fq) ^ s7)]);
#pragma unroll
    for (int n = 0; n < 2; ++n)
#pragma unroll
      for (int kk = 0; kk < 2; ++kk)
        B0[n][kk] = *reinterpret_cast<const bf16x8*>(&LB[bbase + n * 128 + (((kk << 2) + fq) ^ s7)]);
    if (t + 1 < NT) SA(t + 1, 1, buf ^ 1);
    SBAR();
    LGKM0();
    __builtin_amdgcn_s_setprio(1);
#pragma unroll
    for (int m = 0; m < 4; ++m)
#pragma unroll
      for (int n = 0; n < 2; ++n)
#pragma unroll
        for (int kk = 0; kk < 2; ++kk)
          acc[m][n] = __builtin_amdgcn_mfma_f32_16x16x32_bf16(Af[m][kk], B0[n][kk], acc[m][n], 0, 0, 0);
    __builtin_amdgcn_s_setprio(0);
    SBAR();

    // ---- P2: read B-hi; MFMA mlo x nhi ----
#pragma unroll
    for (int n = 0; n < 2; ++n)
#pragma unroll
      for (int kk = 0; kk < 2; ++kk)
        B1[n][kk] = *reinterpret_cast<const bf16x8*>(&LB[bbase + (2 + n) * 128 + (((kk << 2) + fq) ^ s7)]);
    SBAR();
    LGKM0();
    __builtin_amdgcn_s_setprio(1);
#pragma unroll
    for (int m = 0; m < 4; ++m)
#pragma unroll
      for (int n = 0; n < 2; ++n)
#pragma unroll
        for (int kk = 0; kk < 2; ++kk)
          acc[m][2 + n] = __builtin_amdgcn_mfma_f32_16x16x32_bf16(Af[m][kk], B1[n][kk], acc[m][2 + n], 0, 0, 0);
    __builtin_amdgcn_s_setprio(0);
    SBAR();

    // ---- P3: read A-hi; stage B-h0(t+2); MFMA mhi x nhi ----
#pragma unroll
    for (int m = 0; m < 4; ++m)
#pragma unroll
      for (int kk = 0; kk < 2; ++kk)
        Af[m][kk] = *reinterpret_cast<const bf16x8*>(&LA[abase + 512 + m * 128 + (((kk << 2) + fq) ^ s7)]);
    if (t + 2 < NT) SB(t + 2, 0, buf);
    SBAR();
    LGKM0();
    __builtin_amdgcn_s_setprio(1);
#pragma unroll
    for (int m = 0; m < 4; ++m)
#pragma unroll
      for (int n = 0; n < 2; ++n)
#pragma unroll
        for (int kk = 0; kk < 2; ++kk)
          acc[4 + m][2 + n] = __builtin_amdgcn_mfma_f32_16x16x32_bf16(Af[m][kk], B1[n][kk], acc[4 + m][2 + n], 0, 0, 0);
    __builtin_amdgcn_s_setprio(0);
    SBAR();

    // ---- P4: stage B-h1(t+2)+A-h0(t+2); MFMA mhi x nlo; GATE ----
    if (t + 2 < NT) { SB(t + 2, 1, buf); SA(t + 2, 0, buf); }
    __builtin_amdgcn_s_setprio(1);
#pragma unroll
    for (int m = 0; m < 4; ++m)
#pragma unroll
      for (int n = 0; n < 2; ++n)
#pragma unroll
        for (int kk = 0; kk < 2; ++kk)
          acc[4 + m][n] = __builtin_amdgcn_mfma_f32_16x16x32_bf16(Af[m][kk], B0[n][kk], acc[4 + m][n], 0, 0, 0);
    __builtin_amdgcn_s_setprio(0);
    if (t < NT - 2)       { asm volatile("s_waitcnt vmcnt(6)" ::: "memory"); }
    else if (t == NT - 2) { asm volatile("s_waitcnt vmcnt(0)" ::: "memory"); }
    SBAR();
  }

  // epilogue: D row = bm+wm+m*16+fq*4+i, col = bn+wn+n*16+fr
  const int col0 = bn + wn + fr;
#pragma unroll
  for (int m = 0; m < 8; ++m) {
#pragma unroll
    for (int i = 0; i < 4; ++i) {
      const int row = bm + wm + (m << 4) + (fq << 2) + i;
      if (F32OUT) {
        float* rp = reinterpret_cast<float*>(C) + (size_t)row * ldc + col0;
#pragma unroll
        for (int n = 0; n < 4; ++n) rp[n << 4] = acc[m][n][i];
      } else {
        u16* rp = reinterpret_cast<u16*>(C) + (size_t)row * ldc + col0;
#pragma unroll
        for (int n = 0; n < 4; ++n) rp[n << 4] = f2bf(acc[m][n][i]);
      }
    }
  }
}

// ---------------- scatter: fused RoPE-scatter + V-transpose (one launch) ----------------
// blocks [0,40960): RoPE Q/K scatter (Q pre-scaled to log2 domain)
// blocks [40960,41984): V transpose QKV cols [5120,6144) -> Vt[b][kv][d][s]
__global__ __launch_bounds__(256)
void scatter_k(const u16* __restrict__ QKV,
               const float* __restrict__ ctab, const float* __restrict__ stab,
               u16* __restrict__ Qo, u16* __restrict__ Ko, u16* __restrict__ Vt)
{
  __shared__ u16 tile[64][72];
  const int blk = blockIdx.x;
  const int tid = threadIdx.x;
  if (blk < 40960) {
    const int t = blk * 256 + tid;
    const int d = t & 63;
    const int hh = (t >> 6) % ROPE_HEADS;
    const int row = t / (64 * ROPE_HEADS);
    const int b = row >> 11, sq = row & (SEQ - 1);
    const u16* src = QKV + (size_t)row * QKV_DIM + hh * HEAD_DIM;
    const float x1 = bf16f(src[d]);
    const float x2 = bf16f(src[d + 64]);
    const float c = ctab[(sq << 6) + d], sn = stab[(sq << 6) + d];
    float y1 = x1 * c - x2 * sn;
    float y2 = x2 * c + x1 * sn;
    u16* dst;
    if (hh < N_HEADS) {
      const float SC2 = 0.1275170747f;   // (1/sqrt(128)) * log2(e)
      y1 *= SC2; y2 *= SC2;
      dst = Qo + ((size_t)(b * N_HEADS + hh) * SEQ + sq) * HEAD_DIM;
    } else {
      dst = Ko + ((size_t)(b * N_KV + (hh - N_HEADS)) * SEQ + sq) * HEAD_DIM;
    }
    dst[d] = f2bf(y1);
    dst[d + 64] = f2bf(y2);
  } else {
    const int idx = blk - 40960;          // dt(1) | st(5) | kv(3) | b(1)
    const int dt = idx & 1;
    const int st = (idx >> 1) & 31;
    const int kv = (idx >> 6) & 7;
    const int b  = idx >> 9;
    const int s0 = st << 6, d0 = dt << 6;
    const int rl = tid >> 3, cc8 = (tid & 7) << 3;
#pragma unroll
    for (int p = 0; p < 2; ++p) {
      const int sl = rl + (p << 5);
      const u16* src = QKV + (size_t)(b * SEQ + s0 + sl) * QKV_DIM
                     + (N_HEADS + N_KV + kv) * HEAD_DIM + d0 + cc8;
      *reinterpret_cast<uint4*>(&tile[sl][cc8]) = *reinterpret_cast<const uint4*>(src);
    }
    __syncthreads();
#pragma unroll
    for (int p = 0; p < 2; ++p) {
      const int dl = rl + (p << 5);
      u16 tmp[8];
#pragma unroll
      for (int k2 = 0; k2 < 8; ++k2) tmp[k2] = tile[cc8 + k2][dl];
      u16* dst = Vt + ((size_t)(b * N_KV + kv) * HEAD_DIM + d0 + dl) * SEQ + s0 + cc8;
      *reinterpret_cast<uint4*>(dst) = *reinterpret_cast<const uint4*>(tmp);
    }
  }
}

// ---------------- MFMA flash attention (causal GQA, KVBLK=64) ----------------
// R22 version (best measured): KVBLK=64, launch_bounds(512,2), V rows 8 chunks
// with rotation swizzle slot=(c+d)&7 (inverse on stage), permlane pack/reduce.
__global__ __launch_bounds__(512, 2)
void attn_mfma_k(const u16* __restrict__ Q, const u16* __restrict__ K,
                 const u16* __restrict__ Vt, u16* __restrict__ Out)
{
  __shared__ uint4 Ksm[2][1024];
  __shared__ uint4 Vsm[2][1024];
  const int tid  = threadIdx.x;
  const int lane = tid & 63;
  const int w    = tid >> 6;
  const int idx  = blockIdx.x;                    // qrev(5) | b(1) | kvh(3)
  const int kvh  = idx & 7;                       // XCD-pinned KV
  const int b    = (idx >> 3) & 1;
  const int qi   = 31 - (idx >> 4);               // heaviest q-tiles first
  const int q0   = qi << 6;                       // 64-row q-tile base
  const int head = w & 3;
  const int qsub = w >> 2;
  const int h    = (kvh << 2) + head;

  const int ql = lane & 31;
  const int hh = lane >> 5;

  const u16* Qh = Q  + (size_t)(b * N_HEADS + h) * SEQ * HEAD_DIM;
  const u16* Kb = K  + (size_t)(b * N_KV + kvh) * SEQ * HEAD_DIM;
  const u16* Vb = Vt + (size_t)(b * N_KV + kvh) * HEAD_DIM * SEQ;

  int koff[8];
#pragma unroll
  for (int f = 0; f < 8; ++f) koff[f] = (ql << 4) + (((f << 1) + hh) ^ (ql & 15));
  // V read offsets: row d = dblk*32+ql (8 chunks/row), slot = (2j+hh+d)&7 = (2j+hh+ql)&7
  int voff[4][4];
#pragma unroll
  for (int dblk = 0; dblk < 4; ++dblk)
#pragma unroll
    for (int j = 0; j < 4; ++j)
      voff[dblk][j] = ((((dblk << 5) + ql) << 3)) + (((j << 1) + hh + ql) & 7);

  auto stage = [&](int buf, int ks) {
#pragma unroll
    for (int p = 0; p < 2; ++p) {           // K: 64 rows x 16 chunks = 1024
      const int base = (p << 9) + (w << 6);
      const int sl2 = base + lane;
      const int row = sl2 >> 4, cs = sl2 & 15;
      const int g = cs ^ (row & 15);
      const u16* src = Kb + (size_t)(ks + row) * HEAD_DIM + (g << 3);
      __builtin_amdgcn_global_load_lds((const AS1 u32*)src, (AS3 u32*)&Ksm[buf][base], 16, 0, 0);
    }
#pragma unroll
    for (int p = 0; p < 2; ++p) {           // V: 128 rows x 8 chunks = 1024
      const int base = (p << 9) + (w << 6);
      const int sl2 = base + lane;
      const int d = sl2 >> 3, cs = sl2 & 7;
      const int g = (cs - d) & 7;           // inverse of read rotation
      const u16* src = Vb + (size_t)d * SEQ + ks + (g << 3);
      __builtin_amdgcn_global_load_lds((const AS1 u32*)src, (AS3 u32*)&Vsm[buf][base], 16, 0, 0);
    }
  };

  bf16x8 qf[8];
#pragma unroll
  for (int f = 0; f < 8; ++f)
    qf[f] = *reinterpret_cast<const bf16x8*>(Qh + (size_t)(q0 + (qsub << 5) + ql) * HEAD_DIM
                                             + 16 * f + 8 * hh);

  f32x16 o[4];
#pragma unroll
  for (int dblk = 0; dblk < 4; ++dblk)
#pragma unroll
    for (int r = 0; r < 16; ++r) o[dblk][r] = 0.f;
  float m2 = -1e30f, lsum = 0.f;

  stage(0, 0);

#pragma unroll 1
  for (int sb = 0; sb <= qi; ++sb) {
    const int cur = sb & 1;
    __syncthreads();          // drains stage(sb) (vmcnt 0); prev compute done
    if (sb < qi) stage(cur ^ 1, (sb + 1) << 6);   // prefetch under compute

    f32x16 T0, T1;
#pragma unroll
    for (int r = 0; r < 16; ++r) { T0[r] = 0.f; T1[r] = 0.f; }
    __builtin_amdgcn_s_setprio(1);
#pragma unroll
    for (int f = 0; f < 8; ++f) {
      const bf16x8 kf = *reinterpret_cast<const bf16x8*>(&Ksm[cur][koff[f]]);
      T0 = __builtin_amdgcn_mfma_f32_32x32x16_bf16(kf, qf[f], T0, 0, 0, 0);
    }
#pragma unroll
    for (int f = 0; f < 8; ++f) {
      const bf16x8 kf = *reinterpret_cast<const bf16x8*>(&Ksm[cur][koff[f] + 512]);
      T1 = __builtin_amdgcn_mfma_f32_32x32x16_bf16(kf, qf[f], T1, 0, 0, 0);
    }
    __builtin_amdgcn_s_setprio(0);

    if (sb == qi) {
      const int limit = (qsub << 5) + ql;
#pragma unroll
      for (int r = 0; r < 16; ++r) {
        const int kr = (r & 3) + ((r >> 2) << 3) + (hh << 2);
        if (kr > limit)      T0[r] = -1e30f;
        if (kr + 32 > limit) T1[r] = -1e30f;
      }
    }
    // pairwise tree max over 32 + VALU cross-half reduce
    float mx[8];
#pragma unroll
    for (int r = 0; r < 8; ++r)
      mx[r] = fmaxf(fmaxf(T0[2 * r], T0[2 * r + 1]), fmaxf(T1[2 * r], T1[2 * r + 1]));
#pragma unroll
    for (int r = 0; r < 4; ++r) mx[r] = fmaxf(mx[r], mx[r + 4]);
    mx[0] = fmaxf(mx[0], mx[2]);
    mx[1] = fmaxf(mx[1], mx[3]);
    const float mt = crosshalf_max(fmaxf(mx[0], mx[1]));

    if (__any(mt > m2 + 8.f)) {
      const float mnew = fmaxf(m2, mt);
      const float resc = exp2f(m2 - mnew);
      lsum *= resc;
#pragma unroll
      for (int r = 0; r < 16; ++r) {
        const int qr = (r & 3) + ((r >> 2) << 3) + (hh << 2);
        const float rr = __shfl(resc, qr);
#pragma unroll
        for (int dblk = 0; dblk < 4; ++dblk) o[dblk][r] *= rr;
      }
      m2 = mnew;
    }

    float ps = 0.f;
#pragma unroll
    for (int r = 0; r < 16; ++r) {
      const float p0 = exp2f(T0[r] - m2); T0[r] = p0; ps += p0;
      const float p1 = exp2f(T1[r] - m2); T1[r] = p1; ps += p1;
    }
    lsum += crosshalf_sum(ps);

    // ---- pack P (64 keys) -> 4 bf16 A-frags via permlane32_swap ----
    u32 pk[16];
#pragma unroll
    for (int i = 0; i < 8; ++i) {
      pk[i]     = cvt_pk_bf16(T0[2 * i], T0[2 * i + 1]);
      pk[8 + i] = cvt_pk_bf16(T1[2 * i], T1[2 * i + 1]);
    }
    pl32swap(pk[0], pk[2]);  pl32swap(pk[1], pk[3]);
    pl32swap(pk[4], pk[6]);  pl32swap(pk[5], pk[7]);
    pl32swap(pk[8], pk[10]); pl32swap(pk[9], pk[11]);
    pl32swap(pk[12], pk[14]); pl32swap(pk[13], pk[15]);
    bf16x8 a[4];
    a[0] = mk8(pk[0], pk[1], pk[2], pk[3]);
    a[1] = mk8(pk[4], pk[5], pk[6], pk[7]);
    a[2] = mk8(pk[8], pk[9], pk[10], pk[11]);
    a[3] = mk8(pk[12], pk[13], pk[14], pk[15]);

    __builtin_amdgcn_s_setprio(1);
#pragma unroll
    for (int dblk = 0; dblk < 4; ++dblk)
#pragma unroll
      for (int j = 0; j < 4; ++j) {
        const bf16x8 vb = *reinterpret_cast<const bf16x8*>(&Vsm[cur][voff[dblk][j]]);
        o[dblk] = __builtin_amdgcn_mfma_f32_32x32x16_bf16(a[j], vb, o[dblk], 0, 0, 0);
      }
    __builtin_amdgcn_s_setprio(0);
  }

  u16* Ob = Out + (size_t)(b * SEQ + q0 + (qsub << 5)) * HIDDEN_DIM + h * HEAD_DIM + ql;
#pragma unroll
  for (int r = 0; r < 16; ++r) {
    const int qr = (r & 3) + ((r >> 2) << 3) + (hh << 2);
    const float il = 1.0f / __shfl(lsum, qr);
    u16* rp = Ob + (size_t)qr * HIDDEN_DIM;
#pragma unroll
    for (int dblk = 0; dblk < 4; ++dblk)
      rp[dblk * 32] = f2bf(o[dblk][r] * il);
  }
}

// ---------------- launch ----------------
extern "C" void kernel_launch(void* const* d_in, const int* in_sizes, int n_in,
                              void* d_out, int out_size, void* d_ws, size_t ws_size,
                              hipStream_t stream)
{
  const float* hs   = (const float*)d_in[0];
  const float* wqkv = (const float*)d_in[1];
  const float* wo   = (const float*)d_in[2];
  float* out = (float*)d_out;
  char* ws = (char*)d_ws;
  size_t off = 0;
  auto alloc = [&](size_t bytes) -> void* {
    void* p = ws + off;
    off += (bytes + 255) & ~(size_t)255;
    return p;
  };
  u16* Xbf    = (u16*)alloc((size_t)ROWS * HIDDEN_DIM * 2);
  u16* Wqkvbf = (u16*)alloc((size_t)QKV_DIM * HIDDEN_DIM * 2);
  u16* Wobf   = (u16*)alloc((size_t)HIDDEN_DIM * HIDDEN_DIM * 2);
  u16* QKVbf  = (u16*)alloc((size_t)ROWS * QKV_DIM * 2);
  u16* Qbf    = (u16*)alloc((size_t)BSZ * N_HEADS * SEQ * HEAD_DIM * 2);
  u16* Kbf    = (u16*)alloc((size_t)BSZ * N_KV * SEQ * HEAD_DIM * 2);
  u16* Vtbf   = (u16*)alloc((size_t)BSZ * N_KV * SEQ * HEAD_DIM * 2);
  float* ctab = (float*)alloc((size_t)SEQ * 64 * 4);
  float* stab = (float*)alloc((size_t)SEQ * 64 * 4);
  u16* AOut   = (u16*)alloc((size_t)ROWS * HIDDEN_DIM * 2);
  if (off > ws_size) return;

  (void)hipFuncSetAttribute(reinterpret_cast<const void*>(&gemm256_k<0>),
                            hipFuncAttributeMaxDynamicSharedMemorySize, 131072);
  (void)hipFuncSetAttribute(reinterpret_cast<const void*>(&gemm256_k<1>),
                            hipFuncAttributeMaxDynamicSharedMemorySize, 131072);

  // prep: casts (blocks 0..4095, grid-stride) + RoPE tables (blocks 4096..4607)
  prep_k<<<4608, 256, 0, stream>>>((const float4*)hs, (const float4*)wqkv, (const float4*)wo,
                                   (ushort4*)Xbf, (ushort4*)Wqkvbf, (ushort4*)Wobf,
                                   ROWS * HIDDEN_DIM / 4, QKV_DIM * HIDDEN_DIM / 4,
                                   HIDDEN_DIM * HIDDEN_DIM / 4, ctab, stab);

  // GEMM1 split by output columns into two shape-optimal calls:
  //  cols [0,4096): 256x256 8-phase, 16x16 = 256 blocks = exactly 1 CU-round
  gemm256_k<0><<<(ROWS / 256) * (4096 / 256), 512, 131072, stream>>>(
      Xbf, Wqkvbf, (void*)QKVbf, ROWS, 4096, HIDDEN_DIM, QKV_DIM);
  //  cols [4096,6144): 128x128 m97, 32x16 = 512 blocks = exactly 1 round at 2/CU
  gemm_bt_k<0><<<(ROWS / 128) * (2048 / 128), 256, 0, stream>>>(
      Xbf, Wqkvbf + (size_t)4096 * HIDDEN_DIM, (void*)(QKVbf + 4096),
      ROWS, 2048, HIDDEN_DIM, QKV_DIM);

  // scatter: RoPE Q/K (blocks 0..40959) + V transpose (blocks 40960..41983)
  scatter_k<<<40960 + 1024, 256, 0, stream>>>(QKVbf, ctab, stab, Qbf, Kbf, Vtbf);

  attn_mfma_k<<<BSZ * N_KV * (SEQ / 64), 512, 0, stream>>>(Qbf, Kbf, Vtbf, AOut);
  gemm256_k<1><<<(ROWS / 256) * (HIDDEN_DIM / 256), 512, 131072, stream>>>(
      AOut, Wobf, (void*)out, ROWS, HIDDEN_DIM, HIDDEN_DIM, HIDDEN_DIM);
}